// Round 11
// baseline (2420.720 us; speedup 1.0000x reference)
//
#include <hip/hip_runtime.h>

// Fused 2-layer GRU scan. B=256,T=1024,F=64,U=128.
// R18: R12's in-block wave specialization retried with its two failure
// causes fixed. R12 starved (VGPR 84) because waves_per_eu(3) is a MINIMUM
// -- the allocator chased 6 waves/EU; waves_per_eu(3,3) pins the ~168-reg
// budget. And R12 streamed A-frags per-MFMA (exposed LDS latency); here
// they load as upfront arrays. Structure (correctness-verified in R12):
// 16 blocks x 768 thr = 12 waves; waves 0-3 = layer1 (2 colgroups, U1 only
// -- W1 lives in the R14 prepass), waves 4-11 = layer2 (1 cg, W2+U2);
// layer2 lags one step; ONE lockstep s_barrier/step; h1 handoff in LDS.
// Each SIMD holds 1 L1 + 2 L2 waves with different instruction mixes ->
// cross-role MFMA||VALU co-issue (m114) that R9/R15's same-role lockstep
// pairs could not achieve. vs R17 pipeline: no h1 HBM ring (66MB), no
// agent fences, no +CHUNK tail. LDS pad 140 (conflicts 0, R17-proven).
// Consumer z2/r2 use split W2/U2 accumulators (R16: depth 8->4).

#define TT 1024
#define FF 64
#define G3 384
#define XW_BYTES (1024ull * 384 * 256 * 2)

typedef __attribute__((ext_vector_type(8))) __bf16 bf16x8;
typedef __attribute__((ext_vector_type(4))) float f32x4;

#define MFMA(a, b, c) __builtin_amdgcn_mfma_f32_16x16x32_bf16((a), (b), (c), 0, 0, 0)

__device__ __forceinline__ float sigf(float x) {
    return __builtin_amdgcn_rcpf(1.0f + __expf(-x));
}

__device__ __forceinline__ f32x4 unpackv(uint2 v) {
    f32x4 o;
    o[0] = __uint_as_float(v.x << 16);
    o[1] = __uint_as_float(v.x & 0xFFFF0000u);
    o[2] = __uint_as_float(v.y << 16);
    o[3] = __uint_as_float(v.y & 0xFFFF0000u);
    return o;
}

// ---- prepass (R14, measured): ws uint2 idx = ((t*16+rb)*3+g)*512+cg*64+lane
// Gates z,r carry BOTH biases; gate h only the input bias (b_rh separate).
// Each wave handles 8 timesteps: t = blockIdx.y*32 + wave + 4*tt.
__global__ __launch_bounds__(256)
void xw_prepass(
    const float* __restrict__ x, const float* __restrict__ W1,
    const float* __restrict__ b1, unsigned short* __restrict__ ws)
{
    const int tid = threadIdx.x, wave = tid >> 6, lane = tid & 63;
    const int quad = lane >> 4, lc = lane & 15;
    const int rb = blockIdx.x;
    const int t0 = blockIdx.y * 32 + wave;

    bf16x8 xa0[8], xa1[8];
#pragma unroll
    for (int tt = 0; tt < 8; tt++) {
        const float* px =
            x + ((size_t)(rb * 16 + lc) * TT + (t0 + 4 * tt)) * FF + quad * 8;
        f32x4 u0 = *(const f32x4*)px;
        f32x4 u1 = *(const f32x4*)(px + 4);
        f32x4 u2 = *(const f32x4*)(px + 32);
        f32x4 u3 = *(const f32x4*)(px + 36);
#pragma unroll
        for (int j = 0; j < 4; j++) {
            xa0[tt][j] = (__bf16)u0[j]; xa0[tt][j + 4] = (__bf16)u1[j];
            xa1[tt][j] = (__bf16)u2[j]; xa1[tt][j + 4] = (__bf16)u3[j];
        }
    }

    for (int nt = 0; nt < 24; nt++) {
        const int g  = nt >> 3;
        const int cg = nt & 7;
        const int uc = cg * 16 + lc;
        float bi = b1[g * 128 + uc];
        if (g < 2) bi += b1[G3 + g * 128 + uc];
        bf16x8 w0, w1v;
#pragma unroll
        for (int j = 0; j < 8; j++) {
            w0[j]  = (__bf16)W1[(quad * 8 + j) * G3 + g * 128 + uc];
            w1v[j] = (__bf16)W1[(32 + quad * 8 + j) * G3 + g * 128 + uc];
        }
#pragma unroll
        for (int tt = 0; tt < 8; tt++) {
            f32x4 acc = {bi, bi, bi, bi};
            acc = MFMA(xa0[tt], w0, acc);
            acc = MFMA(xa1[tt], w1v, acc);
            unsigned int s0 = __builtin_bit_cast(unsigned short, (__bf16)acc[0]);
            unsigned int s1 = __builtin_bit_cast(unsigned short, (__bf16)acc[1]);
            unsigned int s2 = __builtin_bit_cast(unsigned short, (__bf16)acc[2]);
            unsigned int s3 = __builtin_bit_cast(unsigned short, (__bf16)acc[3]);
            uint2 st;
            st.x = s0 | (s1 << 16);
            st.y = s2 | (s3 << 16);
            uint2* wq = (uint2*)ws
                        + ((size_t)(t0 + 4 * tt) * 16 + rb) * 1536 + lane;
            wq[(size_t)(g * 8 + cg) * 64] = st;
        }
    }
}

// ---- fused scan: 12 waves, 0-3 layer1 (2cg, xw in), 4-11 layer2 (1cg) ----
__global__ __launch_bounds__(768)
__attribute__((amdgpu_waves_per_eu(3, 3)))
void gru_fused(
    const float* __restrict__ U1, const float* __restrict__ b1,
    const float* __restrict__ W2, const float* __restrict__ U2,
    const float* __restrict__ b2, const unsigned short* __restrict__ xw,
    float* __restrict__ out)
{
    const int tid  = threadIdx.x;
    const int wave = tid >> 6;          // 0..11
    const int lane = tid & 63;
    const int quad = lane >> 4;
    const int lc   = lane & 15;
    const int row0 = blockIdx.x * 16;
    const bool isL1 = wave < 4;

    __shared__ __align__(16) __bf16 h1s[2][16][140];
    __shared__ __align__(16) __bf16 h2s[2][16][140];
    for (int i = tid; i < 2 * 16 * 140; i += 768) {
        ((__bf16*)h1s)[i] = (__bf16)0.f;
        ((__bf16*)h2s)[i] = (__bf16)0.f;
    }

    // Producer: U1 frags for 2 colgroups (24 frags = 96 regs).
    // Consumer: W2 (slot 0) + U2 (slot 1) frags for 1 cg (24 frags = 96).
    bf16x8 WB[2][3][4];
    f32x4 bq[4];
    uint2 xwv[2][3];                    // producer only: 1-step prefetch
    const uint2* xqb = (const uint2*)xw + (size_t)blockIdx.x * 1536
                       + (size_t)(wave * 2) * 64 + lane;

    if (isL1) {
#pragma unroll
        for (int gg = 0; gg < 2; gg++) {
            const int uc = wave * 32 + gg * 16 + lc;
#pragma unroll
            for (int g = 0; g < 3; g++)
#pragma unroll
                for (int kt = 0; kt < 4; kt++) {
                    bf16x8 a;
#pragma unroll
                    for (int j = 0; j < 8; j++)
                        a[j] = (__bf16)U1[(kt * 32 + quad * 8 + j) * G3 + g * 128 + uc];
                    WB[gg][g][kt] = a;
                }
            float b = b1[G3 + 256 + uc];
            bq[gg] = (f32x4){b, b, b, b};
        }
#pragma unroll
        for (int gg = 0; gg < 2; gg++)
#pragma unroll
            for (int g = 0; g < 3; g++)
                xwv[gg][g] = xqb[(size_t)g * 512 + gg * 64];
    } else {
        const int uc = (wave - 4) * 16 + lc;
#pragma unroll
        for (int g = 0; g < 3; g++)
#pragma unroll
            for (int kt = 0; kt < 4; kt++) {
                bf16x8 b, c;
#pragma unroll
                for (int j = 0; j < 8; j++) {
                    int k = (kt * 32 + quad * 8 + j) * G3 + g * 128 + uc;
                    b[j] = (__bf16)W2[k];
                    c[j] = (__bf16)U2[k];
                }
                WB[0][g][kt] = b;   // W2
                WB[1][g][kt] = c;   // U2
            }
        float v0 = b2[uc] + b2[G3 + uc];
        float v1 = b2[128 + uc] + b2[G3 + 128 + uc];
        float v2 = b2[256 + uc];
        float v3 = b2[G3 + 256 + uc];
        bq[0] = (f32x4){v0, v0, v0, v0};   // c2z
        bq[1] = (f32x4){v1, v1, v1, v1};   // c2r
        bq[2] = (f32x4){v2, v2, v2, v2};   // b2ih
        bq[3] = (f32x4){v3, v3, v3, v3};   // b2rh
    }

    float hc[2][4] = {{0, 0, 0, 0}, {0, 0, 0, 0}};  // L1: h1c[gg]; L2: hc[0]
    const f32x4 zeroq = {0.f, 0.f, 0.f, 0.f};
    __syncthreads();

// Interval T (PAR=T&1): L1 computes h1(T) from h1s[PAR^1]; L2 computes
// h2(T-1) from h1(T-1)=h1s[PAR^1] and h2(T-2)=h2s[PAR^1]. Writes h1s[PAR],
// h2s[PAR]. All reads sealed by the previous barrier; one barrier/step.
#define STEP(T, PAR)                                                           \
    {                                                                          \
        if (isL1) {                                                            \
            bf16x8 A1[4];                                                      \
            _Pragma("unroll") for (int kt = 0; kt < 4; kt++)                   \
                A1[kt] = *(const bf16x8*)&h1s[PAR ^ 1][lc][kt * 32 + quad * 8];\
            _Pragma("unroll") for (int gg = 0; gg < 2; gg++) {                 \
                f32x4 z1  = unpackv(xwv[gg][0]);                               \
                f32x4 r1  = unpackv(xwv[gg][1]);                               \
                f32x4 xh1 = unpackv(xwv[gg][2]);                               \
                if ((T) + 1 < TT) {                                            \
                    _Pragma("unroll") for (int g = 0; g < 3; g++)              \
                        xwv[gg][g] =                                           \
                            xqb[(size_t)((T) + 1) * 24576 + g * 512 + gg * 64];\
                }                                                              \
                f32x4 rh1 = MFMA(A1[0], WB[gg][2][0], bq[gg]);                 \
                z1  = MFMA(A1[0], WB[gg][0][0], z1);                           \
                r1  = MFMA(A1[0], WB[gg][1][0], r1);                           \
                _Pragma("unroll") for (int kt = 1; kt < 4; kt++) {             \
                    z1  = MFMA(A1[kt], WB[gg][0][kt], z1);                     \
                    r1  = MFMA(A1[kt], WB[gg][1][kt], r1);                     \
                    rh1 = MFMA(A1[kt], WB[gg][2][kt], rh1);                    \
                }                                                              \
                const int uc = wave * 32 + gg * 16 + lc;                       \
                _Pragma("unroll") for (int i = 0; i < 4; i++) {                \
                    float zf = sigf(z1[i]);                                    \
                    float rf = sigf(r1[i]);                                    \
                    float hh = fmaxf(xh1[i] + rf * rh1[i], 0.f);               \
                    hc[gg][i] = fmaf(zf, hc[gg][i] - hh, hh);                  \
                    h1s[PAR][quad * 4 + i][uc] = (__bf16)hc[gg][i];            \
                }                                                              \
            }                                                                  \
        } else {                                                               \
            bf16x8 A1[4], A2[4];                                               \
            _Pragma("unroll") for (int kt = 0; kt < 4; kt++) {                 \
                A1[kt] = *(const bf16x8*)&h1s[PAR ^ 1][lc][kt * 32 + quad * 8];\
                A2[kt] = *(const bf16x8*)&h2s[PAR ^ 1][lc][kt * 32 + quad * 8];\
            }                                                                  \
            /* W2-part (4-deep) + U2-part (4-deep), split accumulators */      \
            f32x4 z2a = MFMA(A1[0], WB[0][0][0], bq[0]);                       \
            f32x4 r2a = MFMA(A1[0], WB[0][1][0], bq[1]);                       \
            f32x4 xh2 = MFMA(A1[0], WB[0][2][0], bq[2]);                       \
            _Pragma("unroll") for (int kt = 1; kt < 4; kt++) {                 \
                z2a = MFMA(A1[kt], WB[0][0][kt], z2a);                         \
                r2a = MFMA(A1[kt], WB[0][1][kt], r2a);                         \
                xh2 = MFMA(A1[kt], WB[0][2][kt], xh2);                         \
            }                                                                  \
            f32x4 z2b = MFMA(A2[0], WB[1][0][0], zeroq);                       \
            f32x4 r2b = MFMA(A2[0], WB[1][1][0], zeroq);                       \
            f32x4 rh2 = MFMA(A2[0], WB[1][2][0], bq[3]);                       \
            _Pragma("unroll") for (int kt = 1; kt < 4; kt++) {                 \
                z2b = MFMA(A2[kt], WB[1][0][kt], z2b);                         \
                r2b = MFMA(A2[kt], WB[1][1][kt], r2b);                         \
                rh2 = MFMA(A2[kt], WB[1][2][kt], rh2);                         \
            }                                                                  \
            f32x4 z2 = z2a + z2b;                                              \
            f32x4 r2 = r2a + r2b;                                              \
            if ((T) > 0) {                                                     \
                _Pragma("unroll") for (int i = 0; i < 4; i++) {                \
                    float zf = sigf(z2[i]);                                    \
                    float rf = sigf(r2[i]);                                    \
                    float hh = fmaxf(xh2[i] + rf * rh2[i], 0.f);               \
                    hc[0][i] = fmaf(zf, hc[0][i] - hh, hh);                    \
                }                                                              \
            }                                                                  \
            const int uc = (wave - 4) * 16 + lc;                               \
            _Pragma("unroll") for (int i = 0; i < 4; i++)                      \
                h2s[PAR][quad * 4 + i][uc] = (__bf16)hc[0][i];                 \
        }                                                                      \
        asm volatile("s_waitcnt lgkmcnt(0)\n\ts_barrier" ::: "memory");        \
    }

    for (int t = 0; t < TT; t += 2) {
        STEP(t, 0)
        STEP(t + 1, 1)
    }
#undef STEP

    if (isL1) {
        // state1 = h1(1023)
#pragma unroll
        for (int gg = 0; gg < 2; gg++) {
            const int uc = wave * 32 + gg * 16 + lc;
#pragma unroll
            for (int i = 0; i < 4; i++) {
                int r = row0 + quad * 4 + i;
                out[32768 + (size_t)r * 128 + uc] = hc[gg][i];
            }
        }
    } else {
        // epilogue: h2(1023) from h1(1023)=h1s[1] and h2(1022)=h2s[1]
        f32x4 z2 = bq[0], r2 = bq[1], xh2 = bq[2], rh2 = bq[3];
#pragma unroll
        for (int kt = 0; kt < 4; kt++) {
            bf16x8 a1 = *(const bf16x8*)&h1s[1][lc][kt * 32 + quad * 8];
            bf16x8 a2 = *(const bf16x8*)&h2s[1][lc][kt * 32 + quad * 8];
            z2  = MFMA(a1, WB[0][0][kt], z2);
            r2  = MFMA(a1, WB[0][1][kt], r2);
            xh2 = MFMA(a1, WB[0][2][kt], xh2);
            z2  = MFMA(a2, WB[1][0][kt], z2);
            r2  = MFMA(a2, WB[1][1][kt], r2);
            rh2 = MFMA(a2, WB[1][2][kt], rh2);
        }
        const int uc = (wave - 4) * 16 + lc;
#pragma unroll
        for (int i = 0; i < 4; i++) {
            float zf = sigf(z2[i]);
            float rf = sigf(r2[i]);
            float hh = fmaxf(xh2[i] + rf * rh2[i], 0.f);
            float h2 = fmaf(zf, hc[0][i] - hh, hh);
            int r = row0 + quad * 4 + i;
            out[(size_t)r * 128 + uc]         = h2;   // x
            out[65536 + (size_t)r * 128 + uc] = h2;   // state2
        }
    }
}

// ---- monolithic fallback (ws too small): proven correct -------------------
__global__ __launch_bounds__(512)
__attribute__((amdgpu_waves_per_eu(2, 2)))
void gru_mono(
    const float* __restrict__ x,  const float* __restrict__ W1,
    const float* __restrict__ U1, const float* __restrict__ b1,
    const float* __restrict__ W2, const float* __restrict__ U2,
    const float* __restrict__ b2, float* __restrict__ out)
{
    const int tid  = threadIdx.x;
    const int wave = tid >> 6;
    const int lane = tid & 63;
    const int quad = lane >> 4;
    const int lc   = lane & 15;
    const int row0 = blockIdx.x * 16;
    const int u    = wave * 16 + lc;

    __shared__ __align__(16) __bf16 h1s[2][16][140];
    __shared__ __align__(16) __bf16 h2s[2][16][140];
    for (int i = tid; i < 2 * 16 * 140; i += 512) {
        ((__bf16*)h1s)[i] = (__bf16)0.f;
        ((__bf16*)h2s)[i] = (__bf16)0.f;
    }

    bf16x8 U1B[3][4], W2B[3][4], U2B[3][4], W1B[3][2];
#pragma unroll
    for (int g = 0; g < 3; g++) {
#pragma unroll
        for (int kt = 0; kt < 4; kt++) {
            bf16x8 a, b, c;
#pragma unroll
            for (int j = 0; j < 8; j++) {
                int k = (kt * 32 + quad * 8 + j) * G3 + g * 128 + u;
                a[j] = (__bf16)U1[k];
                b[j] = (__bf16)W2[k];
                c[j] = (__bf16)U2[k];
            }
            U1B[g][kt] = a; W2B[g][kt] = b; U2B[g][kt] = c;
        }
#pragma unroll
        for (int kt = 0; kt < 2; kt++) {
            bf16x8 a;
#pragma unroll
            for (int j = 0; j < 8; j++)
                a[j] = (__bf16)W1[(kt * 32 + quad * 8 + j) * G3 + g * 128 + u];
            W1B[g][kt] = a;
        }
    }

    const float c1z  = b1[u] + b1[G3 + u];
    const float c1r  = b1[128 + u] + b1[G3 + 128 + u];
    const float b1ih = b1[256 + u];
    const float b1rh = b1[G3 + 256 + u];
    const float c2z  = b2[u] + b2[G3 + u];
    const float c2r  = b2[128 + u] + b2[G3 + 128 + u];
    const float b2ih = b2[256 + u];
    const float b2rh = b2[G3 + 256 + u];
    const f32x4 c1zq  = {c1z, c1z, c1z, c1z};
    const f32x4 c1rq  = {c1r, c1r, c1r, c1r};
    const f32x4 b1ihq = {b1ih, b1ih, b1ih, b1ih};
    const f32x4 b1rhq = {b1rh, b1rh, b1rh, b1rh};
    const f32x4 c2zq  = {c2z, c2z, c2z, c2z};
    const f32x4 c2rq  = {c2r, c2r, c2r, c2r};
    const f32x4 b2ihq = {b2ih, b2ih, b2ih, b2ih};
    const f32x4 b2rhq = {b2rh, b2rh, b2rh, b2rh};

    const float* xrow = x + (size_t)(row0 + lc) * (TT * FF) + quad * 8;
    float h1c[4] = {0, 0, 0, 0};
    float h2c[4] = {0, 0, 0, 0};
    __syncthreads();

#define MSTEP(T, PAR)                                                          \
    {                                                                          \
        bf16x8 A1[4];                                                          \
        _Pragma("unroll") for (int kt = 0; kt < 4; kt++)                       \
            A1[kt] = *(const bf16x8*)&h1s[PAR ^ 1][lc][kt * 32 + quad * 8];    \
        const float* px = xrow + (size_t)(T) * FF;                             \
        f32x4 u0 = *(const f32x4*)px;                                          \
        f32x4 u1 = *(const f32x4*)(px + 4);                                    \
        f32x4 u2 = *(const f32x4*)(px + 32);                                   \
        f32x4 u3 = *(const f32x4*)(px + 36);                                   \
        bf16x8 xa0, xa1;                                                       \
        _Pragma("unroll") for (int j = 0; j < 4; j++) {                        \
            xa0[j] = (__bf16)u0[j]; xa0[j + 4] = (__bf16)u1[j];                \
            xa1[j] = (__bf16)u2[j]; xa1[j + 4] = (__bf16)u3[j];                \
        }                                                                      \
        f32x4 z1  = MFMA(xa0, W1B[0][0], c1zq);                                \
        z1        = MFMA(xa1, W1B[0][1], z1);                                  \
        f32x4 r1  = MFMA(xa0, W1B[1][0], c1rq);                                \
        r1        = MFMA(xa1, W1B[1][1], r1);                                  \
        f32x4 xh1 = MFMA(xa0, W1B[2][0], b1ihq);                               \
        xh1       = MFMA(xa1, W1B[2][1], xh1);                                 \
        f32x4 rh1 = MFMA(A1[0], U1B[2][0], b1rhq);                             \
        z1        = MFMA(A1[0], U1B[0][0], z1);                                \
        r1        = MFMA(A1[0], U1B[1][0], r1);                                \
        _Pragma("unroll") for (int kt = 1; kt < 4; kt++) {                     \
            z1  = MFMA(A1[kt], U1B[0][kt], z1);                                \
            r1  = MFMA(A1[kt], U1B[1][kt], r1);                                \
            rh1 = MFMA(A1[kt], U1B[2][kt], rh1);                               \
        }                                                                      \
        _Pragma("unroll") for (int i = 0; i < 4; i++) {                        \
            float zf = sigf(z1[i]);                                            \
            float rf = sigf(r1[i]);                                            \
            float hh = fmaxf(xh1[i] + rf * rh1[i], 0.f);                       \
            h1c[i] = fmaf(zf, h1c[i] - hh, hh);                                \
            h1s[PAR][quad * 4 + i][u] = (__bf16)h1c[i];                        \
        }                                                                      \
        f32x4 z2  = MFMA(A1[0], W2B[0][0], c2zq);                              \
        f32x4 r2  = MFMA(A1[0], W2B[1][0], c2rq);                              \
        f32x4 xh2 = MFMA(A1[0], W2B[2][0], b2ihq);                             \
        _Pragma("unroll") for (int kt = 1; kt < 4; kt++) {                     \
            z2  = MFMA(A1[kt], W2B[0][kt], z2);                                \
            r2  = MFMA(A1[kt], W2B[1][kt], r2);                                \
            xh2 = MFMA(A1[kt], W2B[2][kt], xh2);                               \
        }                                                                      \
        f32x4 rh2;                                                             \
        {                                                                      \
            bf16x8 A2 = *(const bf16x8*)&h2s[PAR][lc][quad * 8];               \
            rh2 = MFMA(A2, U2B[2][0], b2rhq);                                  \
            z2  = MFMA(A2, U2B[0][0], z2);                                     \
            r2  = MFMA(A2, U2B[1][0], r2);                                     \
        }                                                                      \
        _Pragma("unroll") for (int kt = 1; kt < 4; kt++) {                     \
            bf16x8 A2 = *(const bf16x8*)&h2s[PAR][lc][kt * 32 + quad * 8];     \
            z2  = MFMA(A2, U2B[0][kt], z2);                                    \
            r2  = MFMA(A2, U2B[1][kt], r2);                                    \
            rh2 = MFMA(A2, U2B[2][kt], rh2);                                   \
        }                                                                      \
        if ((T) > 0) {                                                         \
            _Pragma("unroll") for (int i = 0; i < 4; i++) {                    \
                float zf = sigf(z2[i]);                                        \
                float rf = sigf(r2[i]);                                        \
                float hh = fmaxf(xh2[i] + rf * rh2[i], 0.f);                   \
                h2c[i] = fmaf(zf, h2c[i] - hh, hh);                            \
            }                                                                  \
        }                                                                      \
        _Pragma("unroll") for (int i = 0; i < 4; i++)                          \
            h2s[PAR ^ 1][quad * 4 + i][u] = (__bf16)h2c[i];                    \
        asm volatile("s_waitcnt lgkmcnt(0)\n\ts_barrier" ::: "memory");        \
    }

    for (int t = 0; t < TT; t += 2) {
        MSTEP(t, 0)
        MSTEP(t + 1, 1)
    }
#undef MSTEP

    {
        f32x4 z2 = c2zq, r2 = c2rq, xh2 = b2ihq, rh2 = b2rhq;
#pragma unroll
        for (int kt = 0; kt < 4; kt++) {
            bf16x8 a1 = *(const bf16x8*)&h1s[1][lc][kt * 32 + quad * 8];
            bf16x8 a2 = *(const bf16x8*)&h2s[0][lc][kt * 32 + quad * 8];
            z2  = MFMA(a1, W2B[0][kt], z2);
            r2  = MFMA(a1, W2B[1][kt], r2);
            xh2 = MFMA(a1, W2B[2][kt], xh2);
            z2  = MFMA(a2, U2B[0][kt], z2);
            r2  = MFMA(a2, U2B[1][kt], r2);
            rh2 = MFMA(a2, U2B[2][kt], rh2);
        }
#pragma unroll
        for (int i = 0; i < 4; i++) {
            float zf = sigf(z2[i]);
            float rf = sigf(r2[i]);
            float hh = fmaxf(xh2[i] + rf * rh2[i], 0.f);
            h2c[i] = fmaf(zf, h2c[i] - hh, hh);
        }
    }

#pragma unroll
    for (int i = 0; i < 4; i++) {
        int r = row0 + quad * 4 + i;
        out[(size_t)r * 128 + u]         = h2c[i];
        out[32768 + (size_t)r * 128 + u] = h1c[i];
        out[65536 + (size_t)r * 128 + u] = h2c[i];
    }
}

extern "C" void kernel_launch(void* const* d_in, const int* in_sizes, int n_in,
                              void* d_out, int out_size, void* d_ws, size_t ws_size,
                              hipStream_t stream) {
    const float* x  = (const float*)d_in[0];
    const float* W1 = (const float*)d_in[1];
    const float* U1 = (const float*)d_in[2];
    const float* b1 = (const float*)d_in[3];
    const float* W2 = (const float*)d_in[4];
    const float* U2 = (const float*)d_in[5];
    const float* b2 = (const float*)d_in[6];
    float* out = (float*)d_out;

    if (ws_size >= XW_BYTES) {
        unsigned short* ws = (unsigned short*)d_ws;
        xw_prepass<<<dim3(16, 32), dim3(256), 0, stream>>>(x, W1, b1, ws);
        gru_fused<<<dim3(16), dim3(768), 0, stream>>>(
            U1, b1, W2, U2, b2, ws, out);
    } else {
        gru_mono<<<dim3(16), dim3(512), 0, stream>>>(
            x, W1, U1, b1, W2, U2, b2, out);
    }
}

// Round 12
// 1171.663 us; speedup vs baseline: 2.0661x; 2.0661x over previous
//
#include <hip/hip_runtime.h>

// Fused 2-layer GRU scan. B=256,T=1024,F=64,U=128.
// R19: three-role pipeline. R18 confirmed 3 waves/SIMD is register-infeasible
// (168 unified = 84 arch + 84 acc; VGPR_Count=84 again). Within the proven
// R17 2-wave pipeline, the consumer's W2*h1(t) half is NOT recurrent -- it's
// a streaming GEMM over already-published h1. Evict it: 48 blocks, 3 roles.
//   blocks 0-15:  L1 producer -- R17 verbatim (proven 1068us path).
//   blocks 16-31: W2-workers -- chunk-granular barrier-FREE GEMM: read h1
//     ring, compute xw2 = h1@W2 (+z/r biases folded, xh input-bias only),
//     bf16-pack in the proven prepass layout, release flag2 per chunk.
//   blocks 32-47: U2-recurrence -- per step just 12 MFMA (U2*h2) + xw2
//     unpack + gates + one barrier. Half the old consumer's matrix work and
//     none of its W2 chains.
// rb, rb+16, rb+32 land on the SAME XCD (16%8==0) -> rings are L2-local.
// xw2 is a 96MB/16-chunk circular window with U2->worker ack (ws total
// 160MB <= proven-available 192MB). Dependency chain L1 <- worker <- U2 is
// acyclic -> deadlock-free. Worker is faster than the recurrences, so after
// a 2-chunk startup lag the critical path is max(L1 step, U2 step).

#define TT 1024
#define FF 64
#define G3 384
#define NB 16
#define CHUNK 32
#define NCH (TT / CHUNK)
#define XWINC 16                              // xw2 window, chunks
#define XMASK (XWINC * CHUNK - 1)             // 511 step-slot mask
#define FLAGS_TOTAL 8192
#define H1F_BYTES ((size_t)NB * TT * 4096)
#define XW2_BYTES ((size_t)(XWINC * CHUNK) * NB * 12288)
#define PIPE_WS (FLAGS_TOTAL + H1F_BYTES + XW2_BYTES)   // ~160MB

typedef __attribute__((ext_vector_type(8))) __bf16 bf16x8;
typedef __attribute__((ext_vector_type(4))) float f32x4;

#define MFMA(a, b, c) __builtin_amdgcn_mfma_f32_16x16x32_bf16((a), (b), (c), 0, 0, 0)

__device__ __forceinline__ float sigf(float x) {
    return __builtin_amdgcn_rcpf(1.0f + __expf(-x));
}

__device__ __forceinline__ f32x4 unpackv(uint2 v) {
    f32x4 o;
    o[0] = __uint_as_float(v.x << 16);
    o[1] = __uint_as_float(v.x & 0xFFFF0000u);
    o[2] = __uint_as_float(v.y << 16);
    o[3] = __uint_as_float(v.y & 0xFFFF0000u);
    return o;
}

__device__ __forceinline__ void wait_flag(const unsigned int* f) {
    while (__hip_atomic_load(f, __ATOMIC_ACQUIRE, __HIP_MEMORY_SCOPE_AGENT) == 0u)
        __builtin_amdgcn_s_sleep(1);
}

// ---- 48-block pipeline ----------------------------------------------------
__global__ __launch_bounds__(512)
__attribute__((amdgpu_waves_per_eu(2, 2)))
void gru_pipe3(
    const float* __restrict__ x,  const float* __restrict__ W1,
    const float* __restrict__ U1, const float* __restrict__ b1,
    const float* __restrict__ W2, const float* __restrict__ U2,
    const float* __restrict__ b2, unsigned char* __restrict__ ws,
    float* __restrict__ out)
{
    const int tid  = threadIdx.x;
    const int wave = tid >> 6;
    const int lane = tid & 63;
    const int quad = lane >> 4;
    const int lc   = lane & 15;
    const int role = blockIdx.x >> 4;         // 0=L1, 1=worker, 2=U2
    const int rb   = blockIdx.x & 15;
    const int row0 = rb * 16;
    const int u    = wave * 16 + lc;

    unsigned int* flag1 = (unsigned int*)ws + rb * NCH;                 // [16][32]
    unsigned int* flag2 = (unsigned int*)(ws + 2048) + rb * NCH;        // [16][32]
    unsigned int* uackp = (unsigned int*)(ws + 4096) + rb;              // [16]
    unsigned char* h1f  = ws + FLAGS_TOTAL + (size_t)rb * TT * 4096;
    uint2* xw2 = (uint2*)(ws + FLAGS_TOTAL + H1F_BYTES);
    // xw2 uint2 index: ((slot*16 + rb) * 3 + g) * 512 + wave*64 + lane,
    // slot = t & XMASK. Layout identical to the proven xw prepass.

    __shared__ __align__(16) __bf16 hs[2][16][140];   // L1: h1; U2: h2
    if (role != 1) {
        for (int i = tid; i < 2 * 16 * 140; i += 512)
            ((__bf16*)hs)[i] = (__bf16)0.f;
    }

    const f32x4 zeroq = {0.f, 0.f, 0.f, 0.f};

    if (role == 0) {
        // =================== L1 producer (R17 verbatim) ==================
        bf16x8 U1B[3][4], W1B[3][2];
#pragma unroll
        for (int g = 0; g < 3; g++) {
#pragma unroll
            for (int kt = 0; kt < 4; kt++) {
                bf16x8 a;
#pragma unroll
                for (int j = 0; j < 8; j++)
                    a[j] = (__bf16)U1[(kt * 32 + quad * 8 + j) * G3 + g * 128 + u];
                U1B[g][kt] = a;
            }
#pragma unroll
            for (int kt = 0; kt < 2; kt++) {
                bf16x8 a;
#pragma unroll
                for (int j = 0; j < 8; j++)
                    a[j] = (__bf16)W1[(kt * 32 + quad * 8 + j) * G3 + g * 128 + u];
                W1B[g][kt] = a;
            }
        }
        const float c1z  = b1[u] + b1[G3 + u];
        const float c1r  = b1[128 + u] + b1[G3 + 128 + u];
        const float b1ih = b1[256 + u];
        const float b1rh = b1[G3 + 256 + u];
        const f32x4 c1zq  = {c1z, c1z, c1z, c1z};
        const f32x4 c1rq  = {c1r, c1r, c1r, c1r};
        const f32x4 b1ihq = {b1ih, b1ih, b1ih, b1ih};
        const f32x4 b1rhq = {b1rh, b1rh, b1rh, b1rh};

        const float* xrow = x + (size_t)(row0 + lc) * (TT * FF) + quad * 8;
        f32x4 xp0 = *(const f32x4*)(xrow);
        f32x4 xp1 = *(const f32x4*)(xrow + 4);
        f32x4 xp2 = *(const f32x4*)(xrow + 32);
        f32x4 xp3 = *(const f32x4*)(xrow + 36);

        float h1c[4] = {0, 0, 0, 0};
        __syncthreads();

#define PSTEP(T, PAR)                                                          \
    {                                                                          \
        bf16x8 A1[4];                                                          \
        _Pragma("unroll") for (int kt = 0; kt < 4; kt++)                       \
            A1[kt] = *(const bf16x8*)&hs[PAR ^ 1][lc][kt * 32 + quad * 8];     \
        bf16x8 xa0, xa1;                                                       \
        _Pragma("unroll") for (int j = 0; j < 4; j++) {                        \
            xa0[j] = (__bf16)xp0[j]; xa0[j + 4] = (__bf16)xp1[j];              \
            xa1[j] = (__bf16)xp2[j]; xa1[j + 4] = (__bf16)xp3[j];              \
        }                                                                      \
        if ((T) + 1 < TT) {                                                    \
            const float* px = xrow + (size_t)((T) + 1) * FF;                   \
            xp0 = *(const f32x4*)px;                                           \
            xp1 = *(const f32x4*)(px + 4);                                     \
            xp2 = *(const f32x4*)(px + 32);                                    \
            xp3 = *(const f32x4*)(px + 36);                                    \
        }                                                                      \
        f32x4 z1a = MFMA(xa0, W1B[0][0], c1zq);                                \
        f32x4 r1a = MFMA(xa0, W1B[1][0], c1rq);                                \
        f32x4 xh1 = MFMA(xa0, W1B[2][0], b1ihq);                               \
        z1a = MFMA(xa1, W1B[0][1], z1a);                                       \
        r1a = MFMA(xa1, W1B[1][1], r1a);                                       \
        xh1 = MFMA(xa1, W1B[2][1], xh1);                                       \
        f32x4 z1b = MFMA(A1[0], U1B[0][0], zeroq);                             \
        f32x4 r1b = MFMA(A1[0], U1B[1][0], zeroq);                             \
        f32x4 rh1 = MFMA(A1[0], U1B[2][0], b1rhq);                             \
        f32x4 z1d = MFMA(A1[1], U1B[0][1], zeroq);                             \
        f32x4 r1d = MFMA(A1[1], U1B[1][1], zeroq);                             \
        rh1 = MFMA(A1[1], U1B[2][1], rh1);                                     \
        z1b = MFMA(A1[2], U1B[0][2], z1b);                                     \
        r1b = MFMA(A1[2], U1B[1][2], r1b);                                     \
        rh1 = MFMA(A1[2], U1B[2][2], rh1);                                     \
        z1d = MFMA(A1[3], U1B[0][3], z1d);                                     \
        r1d = MFMA(A1[3], U1B[1][3], r1d);                                     \
        rh1 = MFMA(A1[3], U1B[2][3], rh1);                                     \
        if ((T) > 0 && wave == 0) {                                            \
            _Pragma("unroll") for (int kt = 0; kt < 4; kt++)                   \
                *(bf16x8*)(h1f + ((size_t)((T) - 1) * 4 + kt) * 1024           \
                           + lane * 16) = A1[kt];                              \
        }                                                                      \
        f32x4 z1 = z1a + (z1b + z1d);                                          \
        f32x4 r1 = r1a + (r1b + r1d);                                          \
        _Pragma("unroll") for (int i = 0; i < 4; i++) {                        \
            float zf = sigf(z1[i]);                                            \
            float rf = sigf(r1[i]);                                            \
            float hh = fmaxf(xh1[i] + rf * rh1[i], 0.f);                       \
            h1c[i] = fmaf(zf, h1c[i] - hh, hh);                                \
            hs[PAR][quad * 4 + i][u] = (__bf16)h1c[i];                         \
        }                                                                      \
        if (wave == 0 && (T) > 0 && (((T) & (CHUNK - 1)) == 0)) {              \
            __threadfence();                                                   \
            if (lane == 0)                                                     \
                __hip_atomic_store(flag1 + ((T) / CHUNK) - 1, 1u,              \
                                   __ATOMIC_RELEASE,                           \
                                   __HIP_MEMORY_SCOPE_AGENT);                  \
        }                                                                      \
        asm volatile("s_waitcnt lgkmcnt(0)\n\ts_barrier" ::: "memory");        \
    }

        for (int t = 0; t < TT; t += 2) {
            PSTEP(t, 0)
            PSTEP(t + 1, 1)
        }
#undef PSTEP

        if (wave == 0) {
#pragma unroll
            for (int kt = 0; kt < 4; kt++) {
                bf16x8 a = *(const bf16x8*)&hs[1][lc][kt * 32 + quad * 8];
                *(bf16x8*)(h1f + ((size_t)(TT - 1) * 4 + kt) * 1024
                           + lane * 16) = a;
            }
            __threadfence();
            if (lane == 0)
                __hip_atomic_store(flag1 + NCH - 1, 1u, __ATOMIC_RELEASE,
                                   __HIP_MEMORY_SCOPE_AGENT);
        }
#pragma unroll
        for (int i = 0; i < 4; i++) {
            int r = row0 + quad * 4 + i;
            out[32768 + (size_t)r * 128 + u] = h1c[i];
        }
    } else if (role == 1) {
        // =================== W2 worker: streaming GEMM ===================
        bf16x8 W2B[3][4];                 // 12 frags = 48 regs
#pragma unroll
        for (int g = 0; g < 3; g++)
#pragma unroll
            for (int kt = 0; kt < 4; kt++) {
                bf16x8 b;
#pragma unroll
                for (int j = 0; j < 8; j++)
                    b[j] = (__bf16)W2[(kt * 32 + quad * 8 + j) * G3 + g * 128 + u];
                W2B[g][kt] = b;
            }
        const float c2z  = b2[u] + b2[G3 + u];
        const float c2r  = b2[128 + u] + b2[G3 + 128 + u];
        const float b2ih = b2[256 + u];
        const f32x4 c2zq  = {c2z, c2z, c2z, c2z};
        const f32x4 c2rq  = {c2r, c2r, c2r, c2r};
        const f32x4 b2ihq = {b2ih, b2ih, b2ih, b2ih};

        bf16x8 Aa0, Aa1, Aa2, Aa3, Ab0, Ab1, Ab2, Ab3;

#define WSTEP(T, C0, C1, C2, C3, N0, N1, N2, N3)                               \
    {                                                                          \
        if ((T) + 1 < tend) {                                                  \
            const unsigned char* sp =                                          \
                h1f + (size_t)((T) + 1) * 4096 + lane * 16;                    \
            N0 = *(const bf16x8*)(sp);                                         \
            N1 = *(const bf16x8*)(sp + 1024);                                  \
            N2 = *(const bf16x8*)(sp + 2048);                                  \
            N3 = *(const bf16x8*)(sp + 3072);                                  \
        }                                                                      \
        f32x4 z = MFMA(C0, W2B[0][0], c2zq);                                   \
        f32x4 r = MFMA(C0, W2B[1][0], c2rq);                                   \
        f32x4 h = MFMA(C0, W2B[2][0], b2ihq);                                  \
        z = MFMA(C1, W2B[0][1], z);                                            \
        r = MFMA(C1, W2B[1][1], r);                                            \
        h = MFMA(C1, W2B[2][1], h);                                            \
        z = MFMA(C2, W2B[0][2], z);                                            \
        r = MFMA(C2, W2B[1][2], r);                                            \
        h = MFMA(C2, W2B[2][2], h);                                            \
        z = MFMA(C3, W2B[0][3], z);                                            \
        r = MFMA(C3, W2B[1][3], r);                                            \
        h = MFMA(C3, W2B[2][3], h);                                            \
        uint2* xq = xw2 + (((size_t)((T) & XMASK) * 16 + rb) * 3) * 512        \
                    + wave * 64 + lane;                                        \
        f32x4 gv[3] = {z, r, h};                                               \
        _Pragma("unroll") for (int g = 0; g < 3; g++) {                        \
            unsigned int s0 = __builtin_bit_cast(unsigned short, (__bf16)gv[g][0]); \
            unsigned int s1 = __builtin_bit_cast(unsigned short, (__bf16)gv[g][1]); \
            unsigned int s2 = __builtin_bit_cast(unsigned short, (__bf16)gv[g][2]); \
            unsigned int s3 = __builtin_bit_cast(unsigned short, (__bf16)gv[g][3]); \
            uint2 st;                                                          \
            st.x = s0 | (s1 << 16);                                            \
            st.y = s2 | (s3 << 16);                                            \
            xq[(size_t)g * 512] = st;                                          \
        }                                                                      \
    }

        for (int c = 0; c < NCH; c++) {
            wait_flag(flag1 + c);
            if (c >= XWINC) {   // circular window back-pressure vs U2
                while ((int)__hip_atomic_load(uackp, __ATOMIC_ACQUIRE,
                                              __HIP_MEMORY_SCOPE_AGENT)
                       < c - XWINC + 1)
                    __builtin_amdgcn_s_sleep(1);
            }
            const int t0   = c * CHUNK;
            const int tend = t0 + CHUNK;
            {
                const unsigned char* sp = h1f + (size_t)t0 * 4096 + lane * 16;
                Aa0 = *(const bf16x8*)(sp);
                Aa1 = *(const bf16x8*)(sp + 1024);
                Aa2 = *(const bf16x8*)(sp + 2048);
                Aa3 = *(const bf16x8*)(sp + 3072);
            }
            for (int t = t0; t < tend; t += 2) {
                WSTEP(t, Aa0, Aa1, Aa2, Aa3, Ab0, Ab1, Ab2, Ab3)
                WSTEP(t + 1, Ab0, Ab1, Ab2, Ab3, Aa0, Aa1, Aa2, Aa3)
            }
            __threadfence();
            __syncthreads();
            if (tid == 0)
                __hip_atomic_store(flag2 + c, 1u, __ATOMIC_RELEASE,
                                   __HIP_MEMORY_SCOPE_AGENT);
        }
#undef WSTEP
    } else {
        // =================== U2 recurrence ===============================
        bf16x8 U2B[3][4];                 // 12 frags = 48 regs
#pragma unroll
        for (int g = 0; g < 3; g++)
#pragma unroll
            for (int kt = 0; kt < 4; kt++) {
                bf16x8 cfr;
#pragma unroll
                for (int j = 0; j < 8; j++)
                    cfr[j] = (__bf16)U2[(kt * 32 + quad * 8 + j) * G3 + g * 128 + u];
                U2B[g][kt] = cfr;
            }
        const float b2rh = b2[G3 + 256 + u];
        const f32x4 b2rhq = {b2rh, b2rh, b2rh, b2rh};

        const uint2* xqb = xw2 + (size_t)rb * 1536 + wave * 64 + lane;
        uint2 xwv[3];
        float h2c[4] = {0, 0, 0, 0};
        __syncthreads();

#define USTEP(T, PAR)                                                          \
    {                                                                          \
        f32x4 z2  = unpackv(xwv[0]);                                           \
        f32x4 r2  = unpackv(xwv[1]);                                           \
        f32x4 xh2 = unpackv(xwv[2]);                                           \
        if ((T) + 1 < tend) {                                                  \
            _Pragma("unroll") for (int g = 0; g < 3; g++)                      \
                xwv[g] = xqb[(size_t)(((T) + 1) & XMASK) * 24576 + g * 512];   \
        }                                                                      \
        bf16x8 A2[4];                                                          \
        _Pragma("unroll") for (int kt = 0; kt < 4; kt++)                       \
            A2[kt] = *(const bf16x8*)&hs[PAR ^ 1][lc][kt * 32 + quad * 8];     \
        f32x4 rh2 = MFMA(A2[0], U2B[2][0], b2rhq);                             \
        z2 = MFMA(A2[0], U2B[0][0], z2);                                       \
        r2 = MFMA(A2[0], U2B[1][0], r2);                                       \
        _Pragma("unroll") for (int kt = 1; kt < 4; kt++) {                     \
            z2  = MFMA(A2[kt], U2B[0][kt], z2);                                \
            r2  = MFMA(A2[kt], U2B[1][kt], r2);                                \
            rh2 = MFMA(A2[kt], U2B[2][kt], rh2);                               \
        }                                                                      \
        _Pragma("unroll") for (int i = 0; i < 4; i++) {                        \
            float zf = sigf(z2[i]);                                            \
            float rf = sigf(r2[i]);                                            \
            float hh = fmaxf(xh2[i] + rf * rh2[i], 0.f);                       \
            h2c[i] = fmaf(zf, h2c[i] - hh, hh);                                \
            hs[PAR][quad * 4 + i][u] = (__bf16)h2c[i];                         \
        }                                                                      \
        asm volatile("s_waitcnt lgkmcnt(0)\n\ts_barrier" ::: "memory");        \
    }

        for (int c = 0; c < NCH; c++) {
            wait_flag(flag2 + c);
            const int t0   = c * CHUNK;
            const int tend = t0 + CHUNK;
#pragma unroll
            for (int g = 0; g < 3; g++)
                xwv[g] = xqb[(size_t)(t0 & XMASK) * 24576 + g * 512];
            for (int t = t0; t < tend; t += 2) {
                USTEP(t, 0)
                USTEP(t + 1, 1)
            }
            if (tid == 0)
                __hip_atomic_store(uackp, (unsigned int)(c + 1),
                                   __ATOMIC_RELEASE, __HIP_MEMORY_SCOPE_AGENT);
        }
#undef USTEP

        // out: x = h2(1023), state2 = h2(1023)
#pragma unroll
        for (int i = 0; i < 4; i++) {
            int r = row0 + quad * 4 + i;
            out[(size_t)r * 128 + u]         = h2c[i];
            out[65536 + (size_t)r * 128 + u] = h2c[i];
        }
    }
}

// ---- monolithic fallback (ws too small): proven correct -------------------
__global__ __launch_bounds__(512)
__attribute__((amdgpu_waves_per_eu(2, 2)))
void gru_mono(
    const float* __restrict__ x,  const float* __restrict__ W1,
    const float* __restrict__ U1, const float* __restrict__ b1,
    const float* __restrict__ W2, const float* __restrict__ U2,
    const float* __restrict__ b2, float* __restrict__ out)
{
    const int tid  = threadIdx.x;
    const int wave = tid >> 6;
    const int lane = tid & 63;
    const int quad = lane >> 4;
    const int lc   = lane & 15;
    const int row0 = blockIdx.x * 16;
    const int u    = wave * 16 + lc;

    __shared__ __align__(16) __bf16 h1s[2][16][140];
    __shared__ __align__(16) __bf16 h2s[2][16][140];
    for (int i = tid; i < 2 * 16 * 140; i += 512) {
        ((__bf16*)h1s)[i] = (__bf16)0.f;
        ((__bf16*)h2s)[i] = (__bf16)0.f;
    }

    bf16x8 U1B[3][4], W2B[3][4], U2B[3][4], W1B[3][2];
#pragma unroll
    for (int g = 0; g < 3; g++) {
#pragma unroll
        for (int kt = 0; kt < 4; kt++) {
            bf16x8 a, b, c;
#pragma unroll
            for (int j = 0; j < 8; j++) {
                int k = (kt * 32 + quad * 8 + j) * G3 + g * 128 + u;
                a[j] = (__bf16)U1[k];
                b[j] = (__bf16)W2[k];
                c[j] = (__bf16)U2[k];
            }
            U1B[g][kt] = a; W2B[g][kt] = b; U2B[g][kt] = c;
        }
#pragma unroll
        for (int kt = 0; kt < 2; kt++) {
            bf16x8 a;
#pragma unroll
            for (int j = 0; j < 8; j++)
                a[j] = (__bf16)W1[(kt * 32 + quad * 8 + j) * G3 + g * 128 + u];
            W1B[g][kt] = a;
        }
    }

    const float c1z  = b1[u] + b1[G3 + u];
    const float c1r  = b1[128 + u] + b1[G3 + 128 + u];
    const float b1ih = b1[256 + u];
    const float b1rh = b1[G3 + 256 + u];
    const float c2z  = b2[u] + b2[G3 + u];
    const float c2r  = b2[128 + u] + b2[G3 + 128 + u];
    const float b2ih = b2[256 + u];
    const float b2rh = b2[G3 + 256 + u];
    const f32x4 c1zq  = {c1z, c1z, c1z, c1z};
    const f32x4 c1rq  = {c1r, c1r, c1r, c1r};
    const f32x4 b1ihq = {b1ih, b1ih, b1ih, b1ih};
    const f32x4 b1rhq = {b1rh, b1rh, b1rh, b1rh};
    const f32x4 c2zq  = {c2z, c2z, c2z, c2z};
    const f32x4 c2rq  = {c2r, c2r, c2r, c2r};
    const f32x4 b2ihq = {b2ih, b2ih, b2ih, b2ih};
    const f32x4 b2rhq = {b2rh, b2rh, b2rh, b2rh};

    const float* xrow = x + (size_t)(row0 + lc) * (TT * FF) + quad * 8;
    float h1c[4] = {0, 0, 0, 0};
    float h2c[4] = {0, 0, 0, 0};
    __syncthreads();

#define MSTEP(T, PAR)                                                          \
    {                                                                          \
        bf16x8 A1[4];                                                          \
        _Pragma("unroll") for (int kt = 0; kt < 4; kt++)                       \
            A1[kt] = *(const bf16x8*)&h1s[PAR ^ 1][lc][kt * 32 + quad * 8];    \
        const float* px = xrow + (size_t)(T) * FF;                             \
        f32x4 u0 = *(const f32x4*)px;                                          \
        f32x4 u1 = *(const f32x4*)(px + 4);                                    \
        f32x4 u2 = *(const f32x4*)(px + 32);                                   \
        f32x4 u3 = *(const f32x4*)(px + 36);                                   \
        bf16x8 xa0, xa1;                                                       \
        _Pragma("unroll") for (int j = 0; j < 4; j++) {                        \
            xa0[j] = (__bf16)u0[j]; xa0[j + 4] = (__bf16)u1[j];                \
            xa1[j] = (__bf16)u2[j]; xa1[j + 4] = (__bf16)u3[j];                \
        }                                                                      \
        f32x4 z1  = MFMA(xa0, W1B[0][0], c1zq);                                \
        z1        = MFMA(xa1, W1B[0][1], z1);                                  \
        f32x4 r1  = MFMA(xa0, W1B[1][0], c1rq);                                \
        r1        = MFMA(xa1, W1B[1][1], r1);                                  \
        f32x4 xh1 = MFMA(xa0, W1B[2][0], b1ihq);                               \
        xh1       = MFMA(xa1, W1B[2][1], xh1);                                 \
        f32x4 rh1 = MFMA(A1[0], U1B[2][0], b1rhq);                             \
        z1        = MFMA(A1[0], U1B[0][0], z1);                                \
        r1        = MFMA(A1[0], U1B[1][0], r1);                                \
        _Pragma("unroll") for (int kt = 1; kt < 4; kt++) {                     \
            z1  = MFMA(A1[kt], U1B[0][kt], z1);                                \
            r1  = MFMA(A1[kt], U1B[1][kt], r1);                                \
            rh1 = MFMA(A1[kt], U1B[2][kt], rh1);                               \
        }                                                                      \
        _Pragma("unroll") for (int i = 0; i < 4; i++) {                        \
            float zf = sigf(z1[i]);                                            \
            float rf = sigf(r1[i]);                                            \
            float hh = fmaxf(xh1[i] + rf * rh1[i], 0.f);                       \
            h1c[i] = fmaf(zf, h1c[i] - hh, hh);                                \
            h1s[PAR][quad * 4 + i][u] = (__bf16)h1c[i];                        \
        }                                                                      \
        f32x4 z2  = MFMA(A1[0], W2B[0][0], c2zq);                              \
        f32x4 r2  = MFMA(A1[0], W2B[1][0], c2rq);                              \
        f32x4 xh2 = MFMA(A1[0], W2B[2][0], b2ihq);                             \
        _Pragma("unroll") for (int kt = 1; kt < 4; kt++) {                     \
            z2  = MFMA(A1[kt], W2B[0][kt], z2);                                \
            r2  = MFMA(A1[kt], W2B[1][kt], r2);                                \
            xh2 = MFMA(A1[kt], W2B[2][kt], xh2);                               \
        }                                                                      \
        f32x4 rh2;                                                             \
        {                                                                      \
            bf16x8 A2 = *(const bf16x8*)&h2s[PAR][lc][quad * 8];               \
            rh2 = MFMA(A2, U2B[2][0], b2rhq);                                  \
            z2  = MFMA(A2, U2B[0][0], z2);                                     \
            r2  = MFMA(A2, U2B[1][0], r2);                                     \
        }                                                                      \
        _Pragma("unroll") for (int kt = 1; kt < 4; kt++) {                     \
            bf16x8 A2 = *(const bf16x8*)&h2s[PAR][lc][kt * 32 + quad * 8];     \
            z2  = MFMA(A2, U2B[0][kt], z2);                                    \
            r2  = MFMA(A2, U2B[1][kt], r2);                                    \
            rh2 = MFMA(A2, U2B[2][kt], rh2);                                   \
        }                                                                      \
        if ((T) > 0) {                                                         \
            _Pragma("unroll") for (int i = 0; i < 4; i++) {                    \
                float zf = sigf(z2[i]);                                        \
                float rf = sigf(r2[i]);                                        \
                float hh = fmaxf(xh2[i] + rf * rh2[i], 0.f);                   \
                h2c[i] = fmaf(zf, h2c[i] - hh, hh);                            \
            }                                                                  \
        }                                                                      \
        _Pragma("unroll") for (int i = 0; i < 4; i++)                          \
            h2s[PAR ^ 1][quad * 4 + i][u] = (__bf16)h2c[i];                    \
        asm volatile("s_waitcnt lgkmcnt(0)\n\ts_barrier" ::: "memory");        \
    }

    for (int t = 0; t < TT; t += 2) {
        MSTEP(t, 0)
        MSTEP(t + 1, 1)
    }
#undef MSTEP

    {
        f32x4 z2 = c2zq, r2 = c2rq, xh2 = b2ihq, rh2 = b2rhq;
#pragma unroll
        for (int kt = 0; kt < 4; kt++) {
            bf16x8 a1 = *(const bf16x8*)&h1s[1][lc][kt * 32 + quad * 8];
            bf16x8 a2 = *(const bf16x8*)&h2s[0][lc][kt * 32 + quad * 8];
            z2  = MFMA(a1, W2B[0][kt], z2);
            r2  = MFMA(a1, W2B[1][kt], r2);
            xh2 = MFMA(a1, W2B[2][kt], xh2);
            z2  = MFMA(a2, U2B[0][kt], z2);
            r2  = MFMA(a2, U2B[1][kt], r2);
            rh2 = MFMA(a2, U2B[2][kt], rh2);
        }
#pragma unroll
        for (int i = 0; i < 4; i++) {
            float zf = sigf(z2[i]);
            float rf = sigf(r2[i]);
            float hh = fmaxf(xh2[i] + rf * rh2[i], 0.f);
            h2c[i] = fmaf(zf, h2c[i] - hh, hh);
        }
    }

#pragma unroll
    for (int i = 0; i < 4; i++) {
        int r = row0 + quad * 4 + i;
        out[(size_t)r * 128 + u]         = h2c[i];
        out[32768 + (size_t)r * 128 + u] = h1c[i];
        out[65536 + (size_t)r * 128 + u] = h2c[i];
    }
}

extern "C" void kernel_launch(void* const* d_in, const int* in_sizes, int n_in,
                              void* d_out, int out_size, void* d_ws, size_t ws_size,
                              hipStream_t stream) {
    const float* x  = (const float*)d_in[0];
    const float* W1 = (const float*)d_in[1];
    const float* U1 = (const float*)d_in[2];
    const float* b1 = (const float*)d_in[3];
    const float* W2 = (const float*)d_in[4];
    const float* U2 = (const float*)d_in[5];
    const float* b2 = (const float*)d_in[6];
    float* out = (float*)d_out;

    if (ws_size >= PIPE_WS) {
        hipMemsetAsync(d_ws, 0, FLAGS_TOTAL, stream);
        gru_pipe3<<<dim3(3 * NB), dim3(512), 0, stream>>>(
            x, W1, U1, b1, W2, U2, b2, (unsigned char*)d_ws, out);
    } else {
        gru_mono<<<dim3(NB), dim3(512), 0, stream>>>(
            x, W1, U1, b1, W2, U2, b2, out);
    }
}